// Round 11
// baseline (1332.282 us; speedup 1.0000x reference)
//
#include <hip/hip_runtime.h>
#include <hip/hip_bf16.h>

#define HW 4096
#define CIN 192
#define CMID 96

typedef __attribute__((ext_vector_type(8))) short bf16x8;
typedef __attribute__((ext_vector_type(4))) float f32x4;
typedef __attribute__((ext_vector_type(16))) float f32x16;
typedef __attribute__((ext_vector_type(4))) unsigned int u32x4;
typedef __attribute__((ext_vector_type(2))) unsigned int u32x2;

static __device__ __forceinline__ unsigned short f2bf(float f) {
    union { float f; unsigned int u; } v;
    v.f = f;
    unsigned int r = v.u + 0x7fffu + ((v.u >> 16) & 1u);
    return (unsigned short)(r >> 16);
}

static __device__ __forceinline__ void gload16(const void* g, void* l) {
    __builtin_amdgcn_global_load_lds(
        (const __attribute__((address_space(1))) unsigned int*)g,
        (__attribute__((address_space(3))) unsigned int*)l, 16, 0, 0);
}

// (1/64) * log2(e), folded into Q at projection time
#define SCQ (0.015625f * 1.44269504089f)

// ---------------------------------------------------------------------------
// Kernel 0: convert weights to bf16.
// ---------------------------------------------------------------------------
__global__ __launch_bounds__(256) void convw_kernel(
    const float* __restrict__ wq, const float* __restrict__ wk,
    const float* __restrict__ wv, const float* __restrict__ wz,
    unsigned short* __restrict__ wqkvb, unsigned short* __restrict__ wzb)
{
    int idx = blockIdx.x * 256 + threadIdx.x;
    if (idx < 3 * CMID * CIN) {
        int m = idx / (CMID * CIN), r = idx % (CMID * CIN);
        const float* w = (m == 0) ? wq : ((m == 1) ? wk : wv);
        wqkvb[idx] = f2bf(w[r]);
    } else if (idx < 3 * CMID * CIN + CIN * CMID) {
        int r = idx - 3 * CMID * CIN;
        wzb[r] = f2bf(wz[r]);
    }
}

// ---------------------------------------------------------------------------
// Kernel 1: Q/K/V projections (bf16 MFMA).  Unchanged from R9/R10.
// ---------------------------------------------------------------------------
__global__ __launch_bounds__(512) void qkv_kernel(
    const float* __restrict__ x, const float* __restrict__ pe,
    const unsigned short* __restrict__ wqkvb,
    const float* __restrict__ bq, const float* __restrict__ bk,
    const float* __restrict__ bv,
    unsigned short* __restrict__ Q, unsigned short* __restrict__ K,
    unsigned short* __restrict__ V)
{
    const int n = blockIdx.y, bx = blockIdx.x, i0 = bx * 64, t = threadIdx.x;
    __shared__ unsigned short xt[64 * 200];

    #pragma unroll
    for (int it = 0; it < 6; ++it) {
        int q = t + it * 512;
        int c = q >> 4, il4 = (q & 15) << 2;
        f32x4 xv = *(const f32x4*)(x + ((size_t)n * CIN + c) * HW + i0 + il4);
        f32x4 pv = *(const f32x4*)(pe + c * 14400 + bx * 120 + il4);
        float a0 = xv[0] + pv[0], a1 = xv[1] + pv[1];
        float a2 = xv[2] + pv[2], a3 = xv[3] + pv[3];
        unsigned w01, w23;
        asm("v_cvt_pk_bf16_f32 %0, %1, %2" : "=v"(w01) : "v"(a0), "v"(a1));
        asm("v_cvt_pk_bf16_f32 %0, %1, %2" : "=v"(w23) : "v"(a2), "v"(a3));
        xt[(il4 + 0) * 200 + c] = (unsigned short)w01;
        xt[(il4 + 1) * 200 + c] = (unsigned short)(w01 >> 16);
        xt[(il4 + 2) * 200 + c] = (unsigned short)w23;
        xt[(il4 + 3) * 200 + c] = (unsigned short)(w23 >> 16);
    }
    __syncthreads();

    const int w = t >> 6, lane = t & 63, l15 = lane & 15, lg = lane >> 4;
    const int wg = w >> 2;
    const int p0 = (w & 3) * 16;

    bf16x8 af[6];
    #pragma unroll
    for (int f = 0; f < 6; ++f)
        af[f] = *(const bf16x8*)(xt + (p0 + l15) * 200 + f * 32 + lg * 8);

    #pragma unroll
    for (int cc = 0; cc < 9; ++cc) {
        const int ct = wg * 9 + cc;
        const int m = ct / 6, c6 = ct % 6;
        f32x4 acc = (f32x4){0.f, 0.f, 0.f, 0.f};
        const unsigned short* wrow = wqkvb + (ct * 16 + l15) * CIN + lg * 8;
        #pragma unroll
        for (int f = 0; f < 6; ++f) {
            bf16x8 wf = *(const bf16x8*)(wrow + f * 32);
            if (m < 2)
                acc = __builtin_amdgcn_mfma_f32_16x16x32_bf16(wf, af[f], acc, 0, 0, 0);
            else
                acc = __builtin_amdgcn_mfma_f32_16x16x32_bf16(af[f], wf, acc, 0, 0, 0);
        }
        if (m < 2) {
            f32x4 bv4 = *(const f32x4*)(((m == 0) ? bq : bk) + c6 * 16 + lg * 4);
            ushort4 pk4;
            if (m == 0) {
                pk4.x = f2bf((acc[0] + bv4[0]) * SCQ);
                pk4.y = f2bf((acc[1] + bv4[1]) * SCQ);
                pk4.z = f2bf((acc[2] + bv4[2]) * SCQ);
                pk4.w = f2bf((acc[3] + bv4[3]) * SCQ);
            } else {
                pk4.x = f2bf(acc[0] + bv4[0]);
                pk4.y = f2bf(acc[1] + bv4[1]);
                pk4.z = f2bf(acc[2] + bv4[2]);
                pk4.w = f2bf(acc[3] + bv4[3]);
            }
            unsigned short* dst = ((m == 0) ? Q : K) + (size_t)n * HW * CMID;
            *(ushort4*)(dst + (size_t)(i0 + p0 + l15) * CMID + c6 * 16 + lg * 4) = pk4;
        } else {
            const float bias = bv[c6 * 16 + l15];
            ushort4 pk4;
            pk4.x = f2bf(acc[0] + bias); pk4.y = f2bf(acc[1] + bias);
            pk4.z = f2bf(acc[2] + bias); pk4.w = f2bf(acc[3] + bias);
            *(ushort4*)(V + (size_t)n * CMID * HW + (size_t)(c6 * 16 + l15) * HW
                          + i0 + p0 + lg * 4) = pk4;
        }
    }
}

// ---------------------------------------------------------------------------
// Kernel 2: attention core.  8 waves/block (512 threads), 64 q-rows/wave
// (per-wave structure identical to R10); K/V staged once per block and
// shared by all 8 waves (halves staging per compute).  Grid 512 =
// 8 n * 8 iblk * 8 js, fully resident at 2 blocks/CU -> 4 waves/SIMD.
// K: 4 x 8 KB buffers; V: 2 x 12 KB windows.  2 bodies per sync region.
// ---------------------------------------------------------------------------
__global__ __launch_bounds__(512, 4) void attn_kernel(
    const unsigned short* __restrict__ Q, const unsigned short* __restrict__ K,
    const unsigned short* __restrict__ V,
    unsigned short* __restrict__ zp, float* __restrict__ lp)
{
    const int bid = blockIdx.x;           // 512 = 8 n * 8 iblk * 8 js
    const int n    = bid & 7;             // n == XCD: K/V slice L2-resident
    const int iblk = (bid >> 3) & 7;
    const int js   = bid >> 6;            // 0..7

    const int t = threadIdx.x, w = t >> 6, lane = t & 63;
    const int l31 = lane & 31, hi = lane >> 5;
    const int ib = iblk * 512 + w * 64;   // first of 64 q-rows for this wave

    __shared__ unsigned short Ks[4][32 * 128];  // 4 x 8 KB
    __shared__ unsigned short Vs[2][96 * 64];   // 2 x 12 KB  (56 KB total)

    const unsigned short* Qb = Q + (size_t)n * HW * CMID;
    const unsigned short* Kb = K + (size_t)n * HW * CMID;
    const unsigned short* Vb = V + (size_t)n * CMID * HW;

    // Q as B-frag: col = i, k = kc*16 + hi*8 + e
    bf16x8 qf[2][6];
    #pragma unroll
    for (int is = 0; is < 2; ++is)
        #pragma unroll
        for (int kc = 0; kc < 6; ++kc)
            qf[is][kc] = *(const bf16x8*)(Qb + (size_t)(ib + is * 32 + l31) * CMID
                                            + kc * 16 + hi * 8);

    // staging source offsets, pre-swizzled (involution: granule ^= row&7).
    // K: 8 wave-loads cover 32 rows (1 per wave).  V: 12 wave-loads cover 96
    // channels (1 per wave + 1 extra for waves 0-3).
    const int krow = 4 * w + (lane >> 4);                 // 0..31
    const int ksoff = krow * CMID + (((lane & 15) ^ (krow & 7)) * 8);
    const int vc0 = 8 * w + (lane >> 3);                  // 0..63
    const int vsoff0 = vc0 * HW + (((lane & 7) ^ (vc0 & 7)) * 8);
    const int vc1 = 64 + 4 * w + (lane >> 4);             // w<4: 64..79? no:
    // waves 0-3 each cover 8 channels: 64 + 8*w + (lane>>3) -> 64..95
    const int vc1b = 64 + 8 * w + (lane >> 3);
    const int vsoff1 = vc1b * HW + (((lane & 7) ^ (vc1b & 7)) * 8);
    (void)vc1;

    const int j00 = js * 512;

#define STAGE_K(TILE, KB) do {                                                 \
    gload16(Kb + (size_t)(j00 + (TILE) * 32) * CMID + ksoff,                   \
            &Ks[KB][w * 512]);                                                 \
} while (0)
#define STAGE_V(WND, VB) do {                                                  \
    gload16(Vb + (size_t)(j00 + (WND) * 64) + vsoff0, &Vs[VB][w * 512]);       \
    if (w < 4)                                                                 \
        gload16(Vb + (size_t)(j00 + (WND) * 64) + vsoff1,                      \
                &Vs[VB][4096 + w * 512]);                                      \
} while (0)

    f32x16 O[2][3], Lon[2];
    #pragma unroll
    for (int is = 0; is < 2; ++is) {
        #pragma unroll
        for (int cc = 0; cc < 3; ++cc)
            #pragma unroll
            for (int e = 0; e < 16; ++e) O[is][cc][e] = 0.f;
        #pragma unroll
        for (int e = 0; e < 16; ++e) Lon[is][e] = 0.f;
    }

    bf16x8 onef;
    #pragma unroll
    for (int e = 0; e < 8; ++e) onef[e] = (short)0x3F80;  // bf16 1.0

    STAGE_K(0, 0);
    STAGE_K(1, 1);
    STAGE_V(0, 0);
    asm volatile("s_waitcnt vmcnt(0)" ::: "memory");
    __builtin_amdgcn_s_barrier();

#define BODY(KBUF, VBUF, VHALF) do {                                           \
    const unsigned short* Kc = &Ks[KBUF][0];                                   \
    const unsigned short* Vc = &Vs[VBUF][0];                                   \
    f32x16 s0, s1;                                                             \
    _Pragma("unroll") for (int e = 0; e < 16; ++e) { s0[e] = 0.f; s1[e] = 0.f; } \
    __builtin_amdgcn_s_setprio(1);                                             \
    _Pragma("unroll") for (int kc = 0; kc < 6; ++kc) {                         \
        bf16x8 kf = *(const bf16x8*)(Kc + l31 * 128 +                          \
                      (((kc * 2 + hi) ^ (l31 & 7)) << 3));                     \
        s0 = __builtin_amdgcn_mfma_f32_32x32x16_bf16(kf, qf[0][kc], s0, 0, 0, 0); \
        s1 = __builtin_amdgcn_mfma_f32_32x32x16_bf16(kf, qf[1][kc], s1, 0, 0, 0); \
    }                                                                          \
    __builtin_amdgcn_s_setprio(0);                                             \
    unsigned pkk[2][4][2];                                                     \
    _Pragma("unroll") for (int q = 0; q < 4; ++q)                              \
        _Pragma("unroll") for (int rp = 0; rp < 2; ++rp) {                     \
            float lo0 = __builtin_exp2f(s0[q * 4 + 2 * rp]);                   \
            float hh0 = __builtin_exp2f(s0[q * 4 + 2 * rp + 1]);               \
            float lo1 = __builtin_exp2f(s1[q * 4 + 2 * rp]);                   \
            float hh1 = __builtin_exp2f(s1[q * 4 + 2 * rp + 1]);               \
            asm("v_cvt_pk_bf16_f32 %0, %1, %2"                                 \
                : "=v"(pkk[0][q][rp]) : "v"(lo0), "v"(hh0));                   \
            asm("v_cvt_pk_bf16_f32 %0, %1, %2"                                 \
                : "=v"(pkk[1][q][rp]) : "v"(lo1), "v"(hh1));                   \
        }                                                                      \
    u32x4 pfu[2][2];                                                           \
    _Pragma("unroll") for (int is = 0; is < 2; ++is)                           \
        _Pragma("unroll") for (int jc = 0; jc < 2; ++jc) {                     \
            unsigned x0 = pkk[is][2 * jc][0], y0 = pkk[is][2 * jc + 1][0];     \
            unsigned x1 = pkk[is][2 * jc][1], y1 = pkk[is][2 * jc + 1][1];     \
            asm("v_permlane32_swap_b32 %0, %1" : "+v"(y0), "+v"(x0));          \
            asm("v_permlane32_swap_b32 %0, %1" : "+v"(y1), "+v"(x1));          \
            pfu[is][jc][0] = x0; pfu[is][jc][1] = x1;                          \
            pfu[is][jc][2] = y0; pfu[is][jc][3] = y1;                          \
        }                                                                      \
    __builtin_amdgcn_s_setprio(1);                                             \
    _Pragma("unroll") for (int jc = 0; jc < 2; ++jc) {                         \
        bf16x8 pa0 = __builtin_bit_cast(bf16x8, pfu[0][jc]);                   \
        bf16x8 pa1 = __builtin_bit_cast(bf16x8, pfu[1][jc]);                   \
        _Pragma("unroll") for (int cc = 0; cc < 3; ++cc) {                     \
            bf16x8 vf = *(const bf16x8*)(Vc + (cc * 32 + l31) * 64 +           \
                          ((((VHALF) * 4 + jc * 2 + hi) ^ (l31 & 7)) << 3));   \
            O[0][cc] = __builtin_amdgcn_mfma_f32_32x32x16_bf16(pa0, vf, O[0][cc], 0, 0, 0); \
            O[1][cc] = __builtin_amdgcn_mfma_f32_32x32x16_bf16(pa1, vf, O[1][cc], 0, 0, 0); \
        }                                                                      \
        Lon[0] = __builtin_amdgcn_mfma_f32_32x32x16_bf16(pa0, onef, Lon[0], 0, 0, 0); \
        Lon[1] = __builtin_amdgcn_mfma_f32_32x32x16_bf16(pa1, onef, Lon[1], 0, 0, 0); \
    }                                                                          \
    __builtin_amdgcn_s_setprio(0);                                             \
} while (0)

    // 16 tiles: 4 iterations x 2 regions x 2 bodies; buffer ids compile-time.
    for (int tt = 0; tt < 16; tt += 4) {
        // ---- region A: compute tiles tt, tt+1 (K bufs 0,1; V window tt/2)
        {
            STAGE_K(tt + 2, 2);
            STAGE_K(tt + 3, 3);
            const int wn = (tt >> 1) + 1;
            STAGE_V((wn < 8) ? wn : 7, 1);
            BODY(0, 0, 0);
            BODY(1, 0, 1);
            asm volatile("s_waitcnt vmcnt(0)" ::: "memory");
            __builtin_amdgcn_s_barrier();
        }
        // ---- region B: compute tiles tt+2, tt+3 (K bufs 2,3; V window tt/2+1)
        {
            const int k4 = (tt + 4 < 16) ? tt + 4 : 15;
            const int k5 = (tt + 5 < 16) ? tt + 5 : 15;
            STAGE_K(k4, 0);
            STAGE_K(k5, 1);
            const int wn = (tt >> 1) + 2;
            STAGE_V((wn < 8) ? wn : 7, 0);
            BODY(2, 1, 0);
            BODY(3, 1, 1);
            asm volatile("s_waitcnt vmcnt(0)" ::: "memory");
            __builtin_amdgcn_s_barrier();
        }
    }
#undef BODY
#undef STAGE_K
#undef STAGE_V

    // ---- epilogue: unnormalized O (bf16) + row sums (from Lon)
    unsigned short* zb = zp + ((size_t)js * 8 + n) * HW * CMID;
    #pragma unroll
    for (int is = 0; is < 2; ++is)
        #pragma unroll
        for (int cc = 0; cc < 3; ++cc)
            #pragma unroll
            for (int r = 0; r < 16; ++r) {
                int i = ib + is * 32 + (r & 3) + 8 * (r >> 2) + 4 * hi;
                zb[(size_t)i * CMID + cc * 32 + l31] = f2bf(O[is][cc][r]);
            }

    if (l31 == 0) {
        float* lb = lp + ((size_t)js * 8 + n) * HW;
        #pragma unroll
        for (int is = 0; is < 2; ++is)
            #pragma unroll
            for (int r = 0; r < 16; ++r) {
                int i = ib + is * 32 + (r & 3) + 8 * (r >> 2) + 4 * hi;
                lb[i] = Lon[is][r];
            }
    }
}

// ---------------------------------------------------------------------------
// Kernel 3: combine 8 j-slices, normalize, project back (MFMA), residual.
// ---------------------------------------------------------------------------
__global__ __launch_bounds__(256) void zproj_kernel(
    const unsigned short* __restrict__ zp, const float* __restrict__ lp,
    const unsigned short* __restrict__ wzb, const float* __restrict__ bz,
    const float* __restrict__ x, const float* __restrict__ pe,
    float* __restrict__ out)
{
    const int n = blockIdx.y, i0 = blockIdx.x * 64, t = threadIdx.x;
    __shared__ unsigned short zt[64 * 104];
    __shared__ float ll[64];

    if (t < 64) {
        float s = 0.f;
        #pragma unroll
        for (int sl = 0; sl < 8; ++sl)
            s += lp[(size_t)sl * 8 * HW + (size_t)n * HW + i0 + t];
        ll[t] = 1.f / s;
    }
    __syncthreads();

    #pragma unroll
    for (int u = 0; u < 3; ++u) {
        int unit = t + u * 256;
        int i = unit / 12, g = unit % 12;
        size_t gidx = ((size_t)n * HW + i0 + i) * CMID + g * 8;
        float a[8];
        #pragma unroll
        for (int e = 0; e < 8; ++e) a[e] = 0.f;
        #pragma unroll
        for (int sl = 0; sl < 8; ++sl) {
            u32x4 wv = *(const u32x4*)(zp + (size_t)sl * 8 * HW * CMID + gidx);
            #pragma unroll
            for (int k = 0; k < 4; ++k) {
                union { unsigned u; float f; } lo, hi2;
                lo.u = wv[k] << 16;
                hi2.u = wv[k] & 0xffff0000u;
                a[2 * k]     += lo.f;
                a[2 * k + 1] += hi2.f;
            }
        }
        float li = ll[i];
        unsigned ww[4];
        #pragma unroll
        for (int k = 0; k < 4; ++k) {
            float p0 = a[2 * k] * li, p1 = a[2 * k + 1] * li;
            asm("v_cvt_pk_bf16_f32 %0, %1, %2" : "=v"(ww[k]) : "v"(p0), "v"(p1));
        }
        u32x4 wv4 = {ww[0], ww[1], ww[2], ww[3]};
        *(u32x4*)(zt + i * 104 + g * 8) = wv4;
    }
    __syncthreads();

    const int w = t >> 6, lane = t & 63, l15 = lane & 15, lg = lane >> 4;
    const int p0 = w * 16;

    bf16x8 af[3];
    #pragma unroll
    for (int f = 0; f < 3; ++f)
        af[f] = *(const bf16x8*)(zt + (p0 + l15) * 104 + f * 32 + lg * 8);

    #pragma unroll
    for (int ct = 0; ct < 12; ++ct) {
        f32x4 acc = (f32x4){0.f, 0.f, 0.f, 0.f};
        const unsigned short* wrow = wzb + (ct * 16 + l15) * CMID + lg * 8;
        #pragma unroll
        for (int f = 0; f < 3; ++f) {
            bf16x8 wf = *(const bf16x8*)(wrow + f * 32);
            acc = __builtin_amdgcn_mfma_f32_16x16x32_bf16(af[f], wf, acc, 0, 0, 0);
        }
        const int co = ct * 16 + l15;
        const int ibase = i0 + p0 + lg * 4;
        size_t xa = ((size_t)n * CIN + co) * HW + ibase;
        f32x4 xv = *(const f32x4*)(x + xa);
        f32x4 pv = *(const f32x4*)(pe + co * 14400 + blockIdx.x * 120 + p0 + lg * 4);
        const float bias = bz[co];
        f32x4 o;
        #pragma unroll
        for (int r = 0; r < 4; ++r) o[r] = xv[r] + pv[r] + acc[r] + bias;
        *(f32x4*)(out + xa) = o;
    }
}

// ---------------------------------------------------------------------------
extern "C" void kernel_launch(void* const* d_in, const int* in_sizes, int n_in,
                              void* d_out, int out_size, void* d_ws, size_t ws_size,
                              hipStream_t stream) {
    const float* x  = (const float*)d_in[0];
    const float* pe = (const float*)d_in[1];
    const float* wq = (const float*)d_in[2];
    const float* bq = (const float*)d_in[3];
    const float* wk = (const float*)d_in[4];
    const float* bk = (const float*)d_in[5];
    const float* wv = (const float*)d_in[6];
    const float* bv = (const float*)d_in[7];
    const float* wz = (const float*)d_in[8];
    const float* bz = (const float*)d_in[9];
    float* out = (float*)d_out;

    char* ws = (char*)d_ws;
    // ws layout (bytes) — JS=8 (fits: R6 proved ws_size >= 70,451,200):
    //        0: wqkvb bf16 [288][192]          110,592 (pad 131072)
    //   131072: wzb   bf16 [192][96]            36,864 (pad 65536)
    //   196608: Q bf16 [8][4096][96]          6,291,456
    //  6488064: K bf16                        6,291,456
    // 12779520: V^T bf16 [8][96][4096]        6,291,456
    // 19070976: zp bf16 [8][8][4096][96]     50,331,648
    // 69402624: lp f32 [8][8][4096]           1,048,576   (end 70,451,200)
    unsigned short* wqkvb = (unsigned short*)(ws);
    unsigned short* wzb   = (unsigned short*)(ws + 131072);
    unsigned short* Qb    = (unsigned short*)(ws + 196608);
    unsigned short* Kb    = (unsigned short*)(ws + 6488064);
    unsigned short* Vb    = (unsigned short*)(ws + 12779520);
    unsigned short* zpb   = (unsigned short*)(ws + 19070976);
    float*          lpb   = (float*)(ws + 69402624);

    convw_kernel<<<288, 256, 0, stream>>>(wq, wk, wv, wz, wqkvb, wzb);
    qkv_kernel<<<dim3(64, 8), 512, 0, stream>>>(x, pe, wqkvb, bq, bk, bv,
                                                Qb, Kb, Vb);
    attn_kernel<<<512, 512, 0, stream>>>(Qb, Kb, Vb, zpb, lpb);
    zproj_kernel<<<dim3(64, 8), 256, 0, stream>>>(zpb, lpb, wzb, bz, x, pe, out);
}

// Round 12
// 134.051 us; speedup vs baseline: 9.9386x; 9.9386x over previous
//
#include <hip/hip_runtime.h>
#include <hip/hip_bf16.h>

#define HW 4096
#define CIN 192
#define CMID 96

typedef __attribute__((ext_vector_type(8))) short bf16x8;
typedef __attribute__((ext_vector_type(4))) float f32x4;
typedef __attribute__((ext_vector_type(16))) float f32x16;
typedef __attribute__((ext_vector_type(4))) unsigned int u32x4;
typedef __attribute__((ext_vector_type(2))) unsigned int u32x2;

static __device__ __forceinline__ unsigned short f2bf(float f) {
    union { float f; unsigned int u; } v;
    v.f = f;
    unsigned int r = v.u + 0x7fffu + ((v.u >> 16) & 1u);
    return (unsigned short)(r >> 16);
}

static __device__ __forceinline__ void gload16(const void* g, void* l) {
    __builtin_amdgcn_global_load_lds(
        (const __attribute__((address_space(1))) unsigned int*)g,
        (__attribute__((address_space(3))) unsigned int*)l, 16, 0, 0);
}

// (1/64) * log2(e), folded into Q at projection time
#define SCQ (0.015625f * 1.44269504089f)

// ---------------------------------------------------------------------------
// Kernel 0: convert weights to bf16.
// ---------------------------------------------------------------------------
__global__ __launch_bounds__(256) void convw_kernel(
    const float* __restrict__ wq, const float* __restrict__ wk,
    const float* __restrict__ wv, const float* __restrict__ wz,
    unsigned short* __restrict__ wqkvb, unsigned short* __restrict__ wzb)
{
    int idx = blockIdx.x * 256 + threadIdx.x;
    if (idx < 3 * CMID * CIN) {
        int m = idx / (CMID * CIN), r = idx % (CMID * CIN);
        const float* w = (m == 0) ? wq : ((m == 1) ? wk : wv);
        wqkvb[idx] = f2bf(w[r]);
    } else if (idx < 3 * CMID * CIN + CIN * CMID) {
        int r = idx - 3 * CMID * CIN;
        wzb[r] = f2bf(wz[r]);
    }
}

// ---------------------------------------------------------------------------
// Kernel 1: Q/K/V projections (bf16 MFMA).  Unchanged from R9/R10.
// ---------------------------------------------------------------------------
__global__ __launch_bounds__(512) void qkv_kernel(
    const float* __restrict__ x, const float* __restrict__ pe,
    const unsigned short* __restrict__ wqkvb,
    const float* __restrict__ bq, const float* __restrict__ bk,
    const float* __restrict__ bv,
    unsigned short* __restrict__ Q, unsigned short* __restrict__ K,
    unsigned short* __restrict__ V)
{
    const int n = blockIdx.y, bx = blockIdx.x, i0 = bx * 64, t = threadIdx.x;
    __shared__ unsigned short xt[64 * 200];

    #pragma unroll
    for (int it = 0; it < 6; ++it) {
        int q = t + it * 512;
        int c = q >> 4, il4 = (q & 15) << 2;
        f32x4 xv = *(const f32x4*)(x + ((size_t)n * CIN + c) * HW + i0 + il4);
        f32x4 pv = *(const f32x4*)(pe + c * 14400 + bx * 120 + il4);
        float a0 = xv[0] + pv[0], a1 = xv[1] + pv[1];
        float a2 = xv[2] + pv[2], a3 = xv[3] + pv[3];
        unsigned w01, w23;
        asm("v_cvt_pk_bf16_f32 %0, %1, %2" : "=v"(w01) : "v"(a0), "v"(a1));
        asm("v_cvt_pk_bf16_f32 %0, %1, %2" : "=v"(w23) : "v"(a2), "v"(a3));
        xt[(il4 + 0) * 200 + c] = (unsigned short)w01;
        xt[(il4 + 1) * 200 + c] = (unsigned short)(w01 >> 16);
        xt[(il4 + 2) * 200 + c] = (unsigned short)w23;
        xt[(il4 + 3) * 200 + c] = (unsigned short)(w23 >> 16);
    }
    __syncthreads();

    const int w = t >> 6, lane = t & 63, l15 = lane & 15, lg = lane >> 4;
    const int wg = w >> 2;
    const int p0 = (w & 3) * 16;

    bf16x8 af[6];
    #pragma unroll
    for (int f = 0; f < 6; ++f)
        af[f] = *(const bf16x8*)(xt + (p0 + l15) * 200 + f * 32 + lg * 8);

    #pragma unroll
    for (int cc = 0; cc < 9; ++cc) {
        const int ct = wg * 9 + cc;
        const int m = ct / 6, c6 = ct % 6;
        f32x4 acc = (f32x4){0.f, 0.f, 0.f, 0.f};
        const unsigned short* wrow = wqkvb + (ct * 16 + l15) * CIN + lg * 8;
        #pragma unroll
        for (int f = 0; f < 6; ++f) {
            bf16x8 wf = *(const bf16x8*)(wrow + f * 32);
            if (m < 2)
                acc = __builtin_amdgcn_mfma_f32_16x16x32_bf16(wf, af[f], acc, 0, 0, 0);
            else
                acc = __builtin_amdgcn_mfma_f32_16x16x32_bf16(af[f], wf, acc, 0, 0, 0);
        }
        if (m < 2) {
            f32x4 bv4 = *(const f32x4*)(((m == 0) ? bq : bk) + c6 * 16 + lg * 4);
            ushort4 pk4;
            if (m == 0) {
                pk4.x = f2bf((acc[0] + bv4[0]) * SCQ);
                pk4.y = f2bf((acc[1] + bv4[1]) * SCQ);
                pk4.z = f2bf((acc[2] + bv4[2]) * SCQ);
                pk4.w = f2bf((acc[3] + bv4[3]) * SCQ);
            } else {
                pk4.x = f2bf(acc[0] + bv4[0]);
                pk4.y = f2bf(acc[1] + bv4[1]);
                pk4.z = f2bf(acc[2] + bv4[2]);
                pk4.w = f2bf(acc[3] + bv4[3]);
            }
            unsigned short* dst = ((m == 0) ? Q : K) + (size_t)n * HW * CMID;
            *(ushort4*)(dst + (size_t)(i0 + p0 + l15) * CMID + c6 * 16 + lg * 4) = pk4;
        } else {
            const float bias = bv[c6 * 16 + l15];
            ushort4 pk4;
            pk4.x = f2bf(acc[0] + bias); pk4.y = f2bf(acc[1] + bias);
            pk4.z = f2bf(acc[2] + bias); pk4.w = f2bf(acc[3] + bias);
            *(ushort4*)(V + (size_t)n * CMID * HW + (size_t)(c6 * 16 + l15) * HW
                          + i0 + p0 + lg * 4) = pk4;
        }
    }
}

// ---------------------------------------------------------------------------
// Kernel 2: attention core.  8 waves/block (512 threads), 64 q-rows/wave;
// K/V staged once per block, shared by all 8 waves.  Grid 512 = 8n*8iblk*8js,
// 2 blocks/CU (LDS 56 KB) -> 16 waves/CU target.  launch_bounds(512,2):
// 256-reg/wave budget (R11's (512,4) forced 64+64 and spilled to scratch).
// ---------------------------------------------------------------------------
__global__ __launch_bounds__(512, 2) void attn_kernel(
    const unsigned short* __restrict__ Q, const unsigned short* __restrict__ K,
    const unsigned short* __restrict__ V,
    unsigned short* __restrict__ zp, float* __restrict__ lp)
{
    const int bid = blockIdx.x;           // 512 = 8 n * 8 iblk * 8 js
    const int n    = bid & 7;             // n == XCD: K/V slice L2-resident
    const int iblk = (bid >> 3) & 7;
    const int js   = bid >> 6;            // 0..7

    const int t = threadIdx.x, w = t >> 6, lane = t & 63;
    const int l31 = lane & 31, hi = lane >> 5;
    const int ib = iblk * 512 + w * 64;   // first of 64 q-rows for this wave

    __shared__ unsigned short Ks[4][32 * 128];  // 4 x 8 KB
    __shared__ unsigned short Vs[2][96 * 64];   // 2 x 12 KB  (56 KB total)

    const unsigned short* Qb = Q + (size_t)n * HW * CMID;
    const unsigned short* Kb = K + (size_t)n * HW * CMID;
    const unsigned short* Vb = V + (size_t)n * CMID * HW;

    // Q as B-frag: col = i, k = kc*16 + hi*8 + e
    bf16x8 qf[2][6];
    #pragma unroll
    for (int is = 0; is < 2; ++is)
        #pragma unroll
        for (int kc = 0; kc < 6; ++kc)
            qf[is][kc] = *(const bf16x8*)(Qb + (size_t)(ib + is * 32 + l31) * CMID
                                            + kc * 16 + hi * 8);

    // staging source offsets, pre-swizzled (involution: granule ^= row&7).
    const int krow = 4 * w + (lane >> 4);                 // 0..31
    const int ksoff = krow * CMID + (((lane & 15) ^ (krow & 7)) * 8);
    const int vc0 = 8 * w + (lane >> 3);                  // 0..63
    const int vsoff0 = vc0 * HW + (((lane & 7) ^ (vc0 & 7)) * 8);
    const int vc1b = 64 + 8 * w + (lane >> 3);            // 64..95 (w<4)
    const int vsoff1 = vc1b * HW + (((lane & 7) ^ (vc1b & 7)) * 8);

    const int j00 = js * 512;

#define STAGE_K(TILE, KB) do {                                                 \
    gload16(Kb + (size_t)(j00 + (TILE) * 32) * CMID + ksoff,                   \
            &Ks[KB][w * 512]);                                                 \
} while (0)
#define STAGE_V(WND, VB) do {                                                  \
    gload16(Vb + (size_t)(j00 + (WND) * 64) + vsoff0, &Vs[VB][w * 512]);       \
    if (w < 4)                                                                 \
        gload16(Vb + (size_t)(j00 + (WND) * 64) + vsoff1,                      \
                &Vs[VB][4096 + w * 512]);                                      \
} while (0)

    f32x16 O[2][3], Lon[2];
    #pragma unroll
    for (int is = 0; is < 2; ++is) {
        #pragma unroll
        for (int cc = 0; cc < 3; ++cc)
            #pragma unroll
            for (int e = 0; e < 16; ++e) O[is][cc][e] = 0.f;
        #pragma unroll
        for (int e = 0; e < 16; ++e) Lon[is][e] = 0.f;
    }

    bf16x8 onef;
    #pragma unroll
    for (int e = 0; e < 8; ++e) onef[e] = (short)0x3F80;  // bf16 1.0

    STAGE_K(0, 0);
    STAGE_K(1, 1);
    STAGE_V(0, 0);
    asm volatile("s_waitcnt vmcnt(0)" ::: "memory");
    __builtin_amdgcn_s_barrier();

#define BODY(KBUF, VBUF, VHALF) do {                                           \
    const unsigned short* Kc = &Ks[KBUF][0];                                   \
    const unsigned short* Vc = &Vs[VBUF][0];                                   \
    f32x16 s0, s1;                                                             \
    _Pragma("unroll") for (int e = 0; e < 16; ++e) { s0[e] = 0.f; s1[e] = 0.f; } \
    __builtin_amdgcn_s_setprio(1);                                             \
    _Pragma("unroll") for (int kc = 0; kc < 6; ++kc) {                         \
        bf16x8 kf = *(const bf16x8*)(Kc + l31 * 128 +                          \
                      (((kc * 2 + hi) ^ (l31 & 7)) << 3));                     \
        s0 = __builtin_amdgcn_mfma_f32_32x32x16_bf16(kf, qf[0][kc], s0, 0, 0, 0); \
        s1 = __builtin_amdgcn_mfma_f32_32x32x16_bf16(kf, qf[1][kc], s1, 0, 0, 0); \
    }                                                                          \
    __builtin_amdgcn_s_setprio(0);                                             \
    unsigned pkk[2][4][2];                                                     \
    _Pragma("unroll") for (int q = 0; q < 4; ++q)                              \
        _Pragma("unroll") for (int rp = 0; rp < 2; ++rp) {                     \
            float lo0 = __builtin_exp2f(s0[q * 4 + 2 * rp]);                   \
            float hh0 = __builtin_exp2f(s0[q * 4 + 2 * rp + 1]);               \
            float lo1 = __builtin_exp2f(s1[q * 4 + 2 * rp]);                   \
            float hh1 = __builtin_exp2f(s1[q * 4 + 2 * rp + 1]);               \
            asm("v_cvt_pk_bf16_f32 %0, %1, %2"                                 \
                : "=v"(pkk[0][q][rp]) : "v"(lo0), "v"(hh0));                   \
            asm("v_cvt_pk_bf16_f32 %0, %1, %2"                                 \
                : "=v"(pkk[1][q][rp]) : "v"(lo1), "v"(hh1));                   \
        }                                                                      \
    u32x4 pfu[2][2];                                                           \
    _Pragma("unroll") for (int is = 0; is < 2; ++is)                           \
        _Pragma("unroll") for (int jc = 0; jc < 2; ++jc) {                     \
            unsigned x0 = pkk[is][2 * jc][0], y0 = pkk[is][2 * jc + 1][0];     \
            unsigned x1 = pkk[is][2 * jc][1], y1 = pkk[is][2 * jc + 1][1];     \
            asm("v_permlane32_swap_b32 %0, %1" : "+v"(y0), "+v"(x0));          \
            asm("v_permlane32_swap_b32 %0, %1" : "+v"(y1), "+v"(x1));          \
            pfu[is][jc][0] = x0; pfu[is][jc][1] = x1;                          \
            pfu[is][jc][2] = y0; pfu[is][jc][3] = y1;                          \
        }                                                                      \
    __builtin_amdgcn_s_setprio(1);                                             \
    _Pragma("unroll") for (int jc = 0; jc < 2; ++jc) {                         \
        bf16x8 pa0 = __builtin_bit_cast(bf16x8, pfu[0][jc]);                   \
        bf16x8 pa1 = __builtin_bit_cast(bf16x8, pfu[1][jc]);                   \
        _Pragma("unroll") for (int cc = 0; cc < 3; ++cc) {                     \
            bf16x8 vf = *(const bf16x8*)(Vc + (cc * 32 + l31) * 64 +           \
                          ((((VHALF) * 4 + jc * 2 + hi) ^ (l31 & 7)) << 3));   \
            O[0][cc] = __builtin_amdgcn_mfma_f32_32x32x16_bf16(pa0, vf, O[0][cc], 0, 0, 0); \
            O[1][cc] = __builtin_amdgcn_mfma_f32_32x32x16_bf16(pa1, vf, O[1][cc], 0, 0, 0); \
        }                                                                      \
        Lon[0] = __builtin_amdgcn_mfma_f32_32x32x16_bf16(pa0, onef, Lon[0], 0, 0, 0); \
        Lon[1] = __builtin_amdgcn_mfma_f32_32x32x16_bf16(pa1, onef, Lon[1], 0, 0, 0); \
    }                                                                          \
    __builtin_amdgcn_s_setprio(0);                                             \
} while (0)

    // 16 tiles: 4 iterations x 2 regions x 2 bodies; buffer ids compile-time.
    for (int tt = 0; tt < 16; tt += 4) {
        // ---- region A: compute tiles tt, tt+1 (K bufs 0,1; V window tt/2)
        {
            STAGE_K(tt + 2, 2);
            STAGE_K(tt + 3, 3);
            const int wn = (tt >> 1) + 1;
            STAGE_V((wn < 8) ? wn : 7, 1);
            BODY(0, 0, 0);
            BODY(1, 0, 1);
            asm volatile("s_waitcnt vmcnt(0)" ::: "memory");
            __builtin_amdgcn_s_barrier();
        }
        // ---- region B: compute tiles tt+2, tt+3 (K bufs 2,3; V window tt/2+1)
        {
            const int k4 = (tt + 4 < 16) ? tt + 4 : 15;
            const int k5 = (tt + 5 < 16) ? tt + 5 : 15;
            STAGE_K(k4, 0);
            STAGE_K(k5, 1);
            const int wn = (tt >> 1) + 2;
            STAGE_V((wn < 8) ? wn : 7, 0);
            BODY(2, 1, 0);
            BODY(3, 1, 1);
            asm volatile("s_waitcnt vmcnt(0)" ::: "memory");
            __builtin_amdgcn_s_barrier();
        }
    }
#undef BODY
#undef STAGE_K
#undef STAGE_V

    // ---- epilogue: unnormalized O (bf16) + row sums (from Lon)
    unsigned short* zb = zp + ((size_t)js * 8 + n) * HW * CMID;
    #pragma unroll
    for (int is = 0; is < 2; ++is)
        #pragma unroll
        for (int cc = 0; cc < 3; ++cc)
            #pragma unroll
            for (int r = 0; r < 16; ++r) {
                int i = ib + is * 32 + (r & 3) + 8 * (r >> 2) + 4 * hi;
                zb[(size_t)i * CMID + cc * 32 + l31] = f2bf(O[is][cc][r]);
            }

    if (l31 == 0) {
        float* lb = lp + ((size_t)js * 8 + n) * HW;
        #pragma unroll
        for (int is = 0; is < 2; ++is)
            #pragma unroll
            for (int r = 0; r < 16; ++r) {
                int i = ib + is * 32 + (r & 3) + 8 * (r >> 2) + 4 * hi;
                lb[i] = Lon[is][r];
            }
    }
}

// ---------------------------------------------------------------------------
// Kernel 3: combine 8 j-slices, normalize, project back (MFMA), residual.
// ---------------------------------------------------------------------------
__global__ __launch_bounds__(256) void zproj_kernel(
    const unsigned short* __restrict__ zp, const float* __restrict__ lp,
    const unsigned short* __restrict__ wzb, const float* __restrict__ bz,
    const float* __restrict__ x, const float* __restrict__ pe,
    float* __restrict__ out)
{
    const int n = blockIdx.y, i0 = blockIdx.x * 64, t = threadIdx.x;
    __shared__ unsigned short zt[64 * 104];
    __shared__ float ll[64];

    if (t < 64) {
        float s = 0.f;
        #pragma unroll
        for (int sl = 0; sl < 8; ++sl)
            s += lp[(size_t)sl * 8 * HW + (size_t)n * HW + i0 + t];
        ll[t] = 1.f / s;
    }
    __syncthreads();

    #pragma unroll
    for (int u = 0; u < 3; ++u) {
        int unit = t + u * 256;
        int i = unit / 12, g = unit % 12;
        size_t gidx = ((size_t)n * HW + i0 + i) * CMID + g * 8;
        float a[8];
        #pragma unroll
        for (int e = 0; e < 8; ++e) a[e] = 0.f;
        #pragma unroll
        for (int sl = 0; sl < 8; ++sl) {
            u32x4 wv = *(const u32x4*)(zp + (size_t)sl * 8 * HW * CMID + gidx);
            #pragma unroll
            for (int k = 0; k < 4; ++k) {
                union { unsigned u; float f; } lo, hi2;
                lo.u = wv[k] << 16;
                hi2.u = wv[k] & 0xffff0000u;
                a[2 * k]     += lo.f;
                a[2 * k + 1] += hi2.f;
            }
        }
        float li = ll[i];
        unsigned ww[4];
        #pragma unroll
        for (int k = 0; k < 4; ++k) {
            float p0 = a[2 * k] * li, p1 = a[2 * k + 1] * li;
            asm("v_cvt_pk_bf16_f32 %0, %1, %2" : "=v"(ww[k]) : "v"(p0), "v"(p1));
        }
        u32x4 wv4 = {ww[0], ww[1], ww[2], ww[3]};
        *(u32x4*)(zt + i * 104 + g * 8) = wv4;
    }
    __syncthreads();

    const int w = t >> 6, lane = t & 63, l15 = lane & 15, lg = lane >> 4;
    const int p0 = w * 16;

    bf16x8 af[3];
    #pragma unroll
    for (int f = 0; f < 3; ++f)
        af[f] = *(const bf16x8*)(zt + (p0 + l15) * 104 + f * 32 + lg * 8);

    #pragma unroll
    for (int ct = 0; ct < 12; ++ct) {
        f32x4 acc = (f32x4){0.f, 0.f, 0.f, 0.f};
        const unsigned short* wrow = wzb + (ct * 16 + l15) * CMID + lg * 8;
        #pragma unroll
        for (int f = 0; f < 3; ++f) {
            bf16x8 wf = *(const bf16x8*)(wrow + f * 32);
            acc = __builtin_amdgcn_mfma_f32_16x16x32_bf16(af[f], wf, acc, 0, 0, 0);
        }
        const int co = ct * 16 + l15;
        const int ibase = i0 + p0 + lg * 4;
        size_t xa = ((size_t)n * CIN + co) * HW + ibase;
        f32x4 xv = *(const f32x4*)(x + xa);
        f32x4 pv = *(const f32x4*)(pe + co * 14400 + blockIdx.x * 120 + p0 + lg * 4);
        const float bias = bz[co];
        f32x4 o;
        #pragma unroll
        for (int r = 0; r < 4; ++r) o[r] = xv[r] + pv[r] + acc[r] + bias;
        *(f32x4*)(out + xa) = o;
    }
}

// ---------------------------------------------------------------------------
extern "C" void kernel_launch(void* const* d_in, const int* in_sizes, int n_in,
                              void* d_out, int out_size, void* d_ws, size_t ws_size,
                              hipStream_t stream) {
    const float* x  = (const float*)d_in[0];
    const float* pe = (const float*)d_in[1];
    const float* wq = (const float*)d_in[2];
    const float* bq = (const float*)d_in[3];
    const float* wk = (const float*)d_in[4];
    const float* bk = (const float*)d_in[5];
    const float* wv = (const float*)d_in[6];
    const float* bv = (const float*)d_in[7];
    const float* wz = (const float*)d_in[8];
    const float* bz = (const float*)d_in[9];
    float* out = (float*)d_out;

    char* ws = (char*)d_ws;
    // ws layout (bytes) — JS=8 (fits: R6/R11 proved ws_size >= 70,451,200):
    //        0: wqkvb bf16 [288][192]          110,592 (pad 131072)
    //   131072: wzb   bf16 [192][96]            36,864 (pad 65536)
    //   196608: Q bf16 [8][4096][96]          6,291,456
    //  6488064: K bf16                        6,291,456
    // 12779520: V^T bf16 [8][96][4096]        6,291,456
    // 19070976: zp bf16 [8][8][4096][96]     50,331,648
    // 69402624: lp f32 [8][8][4096]           1,048,576   (end 70,451,200)
    unsigned short* wqkvb = (unsigned short*)(ws);
    unsigned short* wzb   = (unsigned short*)(ws + 131072);
    unsigned short* Qb    = (unsigned short*)(ws + 196608);
    unsigned short* Kb    = (unsigned short*)(ws + 6488064);
    unsigned short* Vb    = (unsigned short*)(ws + 12779520);
    unsigned short* zpb   = (unsigned short*)(ws + 19070976);
    float*          lpb   = (float*)(ws + 69402624);

    convw_kernel<<<288, 256, 0, stream>>>(wq, wk, wv, wz, wqkvb, wzb);
    qkv_kernel<<<dim3(64, 8), 512, 0, stream>>>(x, pe, wqkvb, bq, bk, bv,
                                                Qb, Kb, Vb);
    attn_kernel<<<512, 512, 0, stream>>>(Qb, Kb, Vb, zpb, lpb);
    zproj_kernel<<<dim3(64, 8), 256, 0, stream>>>(zpb, lpb, wzb, bz, x, pe, out);
}

// Round 13
// 117.853 us; speedup vs baseline: 11.3046x; 1.1374x over previous
//
#include <hip/hip_runtime.h>
#include <hip/hip_bf16.h>

#define HW 4096
#define CIN 192
#define CMID 96

typedef __attribute__((ext_vector_type(8))) short bf16x8;
typedef __attribute__((ext_vector_type(4))) float f32x4;
typedef __attribute__((ext_vector_type(16))) float f32x16;
typedef __attribute__((ext_vector_type(4))) unsigned int u32x4;

static __device__ __forceinline__ unsigned short f2bf(float f) {
    union { float f; unsigned int u; } v;
    v.f = f;
    unsigned int r = v.u + 0x7fffu + ((v.u >> 16) & 1u);
    return (unsigned short)(r >> 16);
}

// (1/64) * log2(e), folded into Q at projection time
#define SCQ (0.015625f * 1.44269504089f)

// ---------------------------------------------------------------------------
// Kernel 0: convert weights to bf16.
// ---------------------------------------------------------------------------
__global__ __launch_bounds__(256) void convw_kernel(
    const float* __restrict__ wq, const float* __restrict__ wk,
    const float* __restrict__ wv, const float* __restrict__ wz,
    unsigned short* __restrict__ wqkvb, unsigned short* __restrict__ wzb)
{
    int idx = blockIdx.x * 256 + threadIdx.x;
    if (idx < 3 * CMID * CIN) {
        int m = idx / (CMID * CIN), r = idx % (CMID * CIN);
        const float* w = (m == 0) ? wq : ((m == 1) ? wk : wv);
        wqkvb[idx] = f2bf(w[r]);
    } else if (idx < 3 * CMID * CIN + CIN * CMID) {
        int r = idx - 3 * CMID * CIN;
        wzb[r] = f2bf(wz[r]);
    }
}

// ---------------------------------------------------------------------------
// Kernel 1: Q/K/V projections (bf16 MFMA), outputs in MFMA-FRAGMENT-MAJOR
// layout so attention reads are fully coalesced 1KB wave bursts:
//   QF,KF[n][tile=i/32][kc=0..5][lane=hi*32+(i&31)][e=0..7]
//       = {Q,K}[i][kc*16 + hi*8 + e]
//   VF[n][wnd=i/64][cc=0..2][vhalf][jc][lane=hi*32+(ch&31)][e]
//       = V[ch=cc*32+(ch&31)][wnd*64 + (vhalf*4+jc*2+hi)*8 + e]
// ---------------------------------------------------------------------------
__global__ __launch_bounds__(512) void qkv_kernel(
    const float* __restrict__ x, const float* __restrict__ pe,
    const unsigned short* __restrict__ wqkvb,
    const float* __restrict__ bq, const float* __restrict__ bk,
    const float* __restrict__ bv,
    unsigned short* __restrict__ QF, unsigned short* __restrict__ KF,
    unsigned short* __restrict__ VF)
{
    const int n = blockIdx.y, bx = blockIdx.x, i0 = bx * 64, t = threadIdx.x;
    __shared__ unsigned short xt[64 * 200];

    #pragma unroll
    for (int it = 0; it < 6; ++it) {
        int q = t + it * 512;
        int c = q >> 4, il4 = (q & 15) << 2;
        f32x4 xv = *(const f32x4*)(x + ((size_t)n * CIN + c) * HW + i0 + il4);
        f32x4 pv = *(const f32x4*)(pe + c * 14400 + bx * 120 + il4);
        float a0 = xv[0] + pv[0], a1 = xv[1] + pv[1];
        float a2 = xv[2] + pv[2], a3 = xv[3] + pv[3];
        unsigned w01, w23;
        asm("v_cvt_pk_bf16_f32 %0, %1, %2" : "=v"(w01) : "v"(a0), "v"(a1));
        asm("v_cvt_pk_bf16_f32 %0, %1, %2" : "=v"(w23) : "v"(a2), "v"(a3));
        xt[(il4 + 0) * 200 + c] = (unsigned short)w01;
        xt[(il4 + 1) * 200 + c] = (unsigned short)(w01 >> 16);
        xt[(il4 + 2) * 200 + c] = (unsigned short)w23;
        xt[(il4 + 3) * 200 + c] = (unsigned short)(w23 >> 16);
    }
    __syncthreads();

    const int w = t >> 6, lane = t & 63, l15 = lane & 15, lg = lane >> 4;
    const int wg = w >> 2;
    const int p0 = (w & 3) * 16;

    bf16x8 af[6];
    #pragma unroll
    for (int f = 0; f < 6; ++f)
        af[f] = *(const bf16x8*)(xt + (p0 + l15) * 200 + f * 32 + lg * 8);

    #pragma unroll
    for (int cc = 0; cc < 9; ++cc) {
        const int ct = wg * 9 + cc;
        const int m = ct / 6, c6 = ct % 6;
        f32x4 acc = (f32x4){0.f, 0.f, 0.f, 0.f};
        const unsigned short* wrow = wqkvb + (ct * 16 + l15) * CIN + lg * 8;
        #pragma unroll
        for (int f = 0; f < 6; ++f) {
            bf16x8 wf = *(const bf16x8*)(wrow + f * 32);
            if (m < 2)
                acc = __builtin_amdgcn_mfma_f32_16x16x32_bf16(wf, af[f], acc, 0, 0, 0);
            else
                acc = __builtin_amdgcn_mfma_f32_16x16x32_bf16(af[f], wf, acc, 0, 0, 0);
        }
        if (m < 2) {
            // lane holds channel c = c6*16 + lg*4 + r  for pixel p = i0+p0+l15
            f32x4 bv4 = *(const f32x4*)(((m == 0) ? bq : bk) + c6 * 16 + lg * 4);
            ushort4 pk4;
            if (m == 0) {
                pk4.x = f2bf((acc[0] + bv4[0]) * SCQ);
                pk4.y = f2bf((acc[1] + bv4[1]) * SCQ);
                pk4.z = f2bf((acc[2] + bv4[2]) * SCQ);
                pk4.w = f2bf((acc[3] + bv4[3]) * SCQ);
            } else {
                pk4.x = f2bf(acc[0] + bv4[0]);
                pk4.y = f2bf(acc[1] + bv4[1]);
                pk4.z = f2bf(acc[2] + bv4[2]);
                pk4.w = f2bf(acc[3] + bv4[3]);
            }
            // fragment-major: tile = p>>5, kc = c6, hi = lg>>1, e0 = (lg&1)*4
            const int p = i0 + p0 + l15;
            unsigned short* dst = (m == 0) ? QF : KF;
            size_t fa = ((((size_t)n * 128 + (p >> 5)) * 6 + c6) * 64
                         + (lg >> 1) * 32 + (p & 31)) * 8 + (lg & 1) * 4;
            *(ushort4*)(dst + fa) = pk4;
        } else {
            // lane holds pixel p = i0+p0+lg*4+r  for channel ch = c6*16+l15
            const float bias = bv[c6 * 16 + l15];
            ushort4 pk4;
            pk4.x = f2bf(acc[0] + bias); pk4.y = f2bf(acc[1] + bias);
            pk4.z = f2bf(acc[2] + bias); pk4.w = f2bf(acc[3] + bias);
            const int ch = c6 * 16 + l15;
            const int slot = 2 * (w & 3) + (lg >> 1);   // (p&63)>>3
            size_t fa = ((((((size_t)n * 64 + bx) * 3 + (ch >> 5)) * 2
                           + (slot >> 2)) * 2 + ((slot >> 1) & 1)) * 64
                         + (slot & 1) * 32 + (ch & 31)) * 8 + (lg & 1) * 4;
            *(ushort4*)(VF + fa) = pk4;
        }
    }
}

// ---------------------------------------------------------------------------
// Kernel 2: attention core — NO LDS, NO barriers.  Fragments read directly
// from L2 in fragment-major layout (coalesced 1KB wave bursts).  64 q-rows
// per wave, 4 waves/block (independent), grid 512 = 8n * 16iblk * 4js,
// n == XCD so each XCD's K/V slice (~3 MB) stays L2-resident.
// In-register softmax (no-max, Q pre-scaled); permlane32_swap exchange;
// VALU row-sums.
// ---------------------------------------------------------------------------
__global__ __launch_bounds__(256, 2) void attn_kernel(
    const unsigned short* __restrict__ QF, const unsigned short* __restrict__ KF,
    const unsigned short* __restrict__ VF,
    unsigned short* __restrict__ zp, float* __restrict__ lp)
{
    const int bid = blockIdx.x;           // 512 = 8 n * 16 iblk * 4 js
    const int n    = bid & 7;
    const int iblk = (bid >> 3) & 15;
    const int js   = bid >> 7;            // 0..3

    const int t = threadIdx.x, w = t >> 6, lane = t & 63;
    const int l31 = lane & 31, hi = lane >> 5;
    const int ib = iblk * 256 + w * 64;

    const unsigned short* QFb = QF + (size_t)n * 128 * 3072;  // 6*512
    const unsigned short* KFb = KF + (size_t)n * 128 * 3072;
    const unsigned short* VFb = VF + (size_t)n * 64 * 6144;   // 3*2*2*512

    // Q fragments, hoisted (coalesced: lane*8 within each 512-short burst)
    bf16x8 qf[2][6];
    #pragma unroll
    for (int is = 0; is < 2; ++is)
        #pragma unroll
        for (int kc = 0; kc < 6; ++kc)
            qf[is][kc] = *(const bf16x8*)(QFb + ((size_t)((ib >> 5) + is) * 6 + kc) * 512
                                          + lane * 8);

    f32x16 O[2][3];
    #pragma unroll
    for (int is = 0; is < 2; ++is)
        #pragma unroll
        for (int cc = 0; cc < 3; ++cc)
            #pragma unroll
            for (int e = 0; e < 16; ++e) O[is][cc][e] = 0.f;
    float lsum0 = 0.f, lsum1 = 0.f;

    for (int tt = 0; tt < 32; ++tt) {
        const int jt = js * 32 + tt;
        const unsigned short* Kt = KFb + (size_t)jt * 3072;

        // ---- all 12 fragment loads issued up front (independent, coalesced)
        bf16x8 kf[6];
        #pragma unroll
        for (int kc = 0; kc < 6; ++kc)
            kf[kc] = *(const bf16x8*)(Kt + kc * 512 + lane * 8);
        bf16x8 vf[2][3];
        #pragma unroll
        for (int jc = 0; jc < 2; ++jc)
            #pragma unroll
            for (int cc = 0; cc < 3; ++cc)
                vf[jc][cc] = *(const bf16x8*)(VFb
                    + ((size_t)((jt >> 1) * 3 + cc) * 4 + (jt & 1) * 2 + jc) * 512
                    + lane * 8);

        // ---- S^T = mfma(K, Q): D[j][i]
        f32x16 s0, s1;
        #pragma unroll
        for (int e = 0; e < 16; ++e) { s0[e] = 0.f; s1[e] = 0.f; }
        __builtin_amdgcn_s_setprio(1);
        #pragma unroll
        for (int kc = 0; kc < 6; ++kc) {
            s0 = __builtin_amdgcn_mfma_f32_32x32x16_bf16(kf[kc], qf[0][kc], s0, 0, 0, 0);
            s1 = __builtin_amdgcn_mfma_f32_32x32x16_bf16(kf[kc], qf[1][kc], s1, 0, 0, 0);
        }
        __builtin_amdgcn_s_setprio(0);

        // ---- P = exp2(S); in-lane row sums; pack to bf16
        unsigned pkk[2][4][2];
        #pragma unroll
        for (int q = 0; q < 4; ++q)
            #pragma unroll
            for (int rp = 0; rp < 2; ++rp) {
                float lo0 = __builtin_exp2f(s0[q * 4 + 2 * rp]);
                float hh0 = __builtin_exp2f(s0[q * 4 + 2 * rp + 1]);
                float lo1 = __builtin_exp2f(s1[q * 4 + 2 * rp]);
                float hh1 = __builtin_exp2f(s1[q * 4 + 2 * rp + 1]);
                lsum0 += lo0 + hh0;
                lsum1 += lo1 + hh1;
                asm("v_cvt_pk_bf16_f32 %0, %1, %2"
                    : "=v"(pkk[0][q][rp]) : "v"(lo0), "v"(hh0));
                asm("v_cvt_pk_bf16_f32 %0, %1, %2"
                    : "=v"(pkk[1][q][rp]) : "v"(lo1), "v"(hh1));
            }

        // ---- redistribute to PV A-frags (lane<32 <-> lane>=32 halves)
        u32x4 pfu[2][2];
        #pragma unroll
        for (int is = 0; is < 2; ++is)
            #pragma unroll
            for (int jc = 0; jc < 2; ++jc) {
                unsigned x0 = pkk[is][2 * jc][0], y0 = pkk[is][2 * jc + 1][0];
                unsigned x1 = pkk[is][2 * jc][1], y1 = pkk[is][2 * jc + 1][1];
                asm("v_permlane32_swap_b32 %0, %1" : "+v"(y0), "+v"(x0));
                asm("v_permlane32_swap_b32 %0, %1" : "+v"(y1), "+v"(x1));
                pfu[is][jc][0] = x0; pfu[is][jc][1] = x1;
                pfu[is][jc][2] = y0; pfu[is][jc][3] = y1;
            }

        // ---- O += P V
        __builtin_amdgcn_s_setprio(1);
        #pragma unroll
        for (int jc = 0; jc < 2; ++jc) {
            bf16x8 pa0 = __builtin_bit_cast(bf16x8, pfu[0][jc]);
            bf16x8 pa1 = __builtin_bit_cast(bf16x8, pfu[1][jc]);
            #pragma unroll
            for (int cc = 0; cc < 3; ++cc) {
                O[0][cc] = __builtin_amdgcn_mfma_f32_32x32x16_bf16(pa0, vf[jc][cc], O[0][cc], 0, 0, 0);
                O[1][cc] = __builtin_amdgcn_mfma_f32_32x32x16_bf16(pa1, vf[jc][cc], O[1][cc], 0, 0, 0);
            }
        }
        __builtin_amdgcn_s_setprio(0);
    }

    // ---- epilogue: unnormalized O (bf16) + row sums
    unsigned short* zb = zp + ((size_t)js * 8 + n) * HW * CMID;
    #pragma unroll
    for (int is = 0; is < 2; ++is)
        #pragma unroll
        for (int cc = 0; cc < 3; ++cc)
            #pragma unroll
            for (int r = 0; r < 16; ++r) {
                int i = ib + is * 32 + (r & 3) + 8 * (r >> 2) + 4 * hi;
                zb[(size_t)i * CMID + cc * 32 + l31] = f2bf(O[is][cc][r]);
            }

    lsum0 += __shfl_xor(lsum0, 32, 64);
    lsum1 += __shfl_xor(lsum1, 32, 64);
    if (hi == 0) {
        float* lb = lp + ((size_t)js * 8 + n) * HW;
        lb[ib + l31]      = lsum0;
        lb[ib + 32 + l31] = lsum1;
    }
}

// ---------------------------------------------------------------------------
// Kernel 3: combine 4 j-slices, normalize, project back (MFMA), residual.
// (R10-proven JS=4 version.)
// ---------------------------------------------------------------------------
__global__ __launch_bounds__(256) void zproj_kernel(
    const unsigned short* __restrict__ zp, const float* __restrict__ lp,
    const unsigned short* __restrict__ wzb, const float* __restrict__ bz,
    const float* __restrict__ x, const float* __restrict__ pe,
    float* __restrict__ out)
{
    const int n = blockIdx.y, i0 = blockIdx.x * 64, t = threadIdx.x;
    __shared__ unsigned short zt[64 * 104];
    __shared__ float ll[64];

    if (t < 64) {
        float s = 0.f;
        #pragma unroll
        for (int sl = 0; sl < 4; ++sl)
            s += lp[(size_t)sl * 8 * HW + (size_t)n * HW + i0 + t];
        ll[t] = 1.f / s;
    }
    __syncthreads();

    #pragma unroll
    for (int u = 0; u < 3; ++u) {
        int unit = t + u * 256;
        int i = unit / 12, g = unit % 12;
        size_t gidx = ((size_t)n * HW + i0 + i) * CMID + g * 8;
        float a[8];
        #pragma unroll
        for (int e = 0; e < 8; ++e) a[e] = 0.f;
        #pragma unroll
        for (int sl = 0; sl < 4; ++sl) {
            u32x4 wv = *(const u32x4*)(zp + (size_t)sl * 8 * HW * CMID + gidx);
            #pragma unroll
            for (int k = 0; k < 4; ++k) {
                union { unsigned u; float f; } lo, hi2;
                lo.u = wv[k] << 16;
                hi2.u = wv[k] & 0xffff0000u;
                a[2 * k]     += lo.f;
                a[2 * k + 1] += hi2.f;
            }
        }
        float li = ll[i];
        unsigned ww[4];
        #pragma unroll
        for (int k = 0; k < 4; ++k) {
            float p0 = a[2 * k] * li, p1 = a[2 * k + 1] * li;
            asm("v_cvt_pk_bf16_f32 %0, %1, %2" : "=v"(ww[k]) : "v"(p0), "v"(p1));
        }
        u32x4 wv4 = {ww[0], ww[1], ww[2], ww[3]};
        *(u32x4*)(zt + i * 104 + g * 8) = wv4;
    }
    __syncthreads();

    const int w = t >> 6, lane = t & 63, l15 = lane & 15, lg = lane >> 4;
    const int p0 = w * 16;

    bf16x8 af[3];
    #pragma unroll
    for (int f = 0; f < 3; ++f)
        af[f] = *(const bf16x8*)(zt + (p0 + l15) * 104 + f * 32 + lg * 8);

    #pragma unroll
    for (int ct = 0; ct < 12; ++ct) {
        f32x4 acc = (f32x4){0.f, 0.f, 0.f, 0.f};
        const unsigned short* wrow = wzb + (ct * 16 + l15) * CMID + lg * 8;
        #pragma unroll
        for (int f = 0; f < 3; ++f) {
            bf16x8 wf = *(const bf16x8*)(wrow + f * 32);
            acc = __builtin_amdgcn_mfma_f32_16x16x32_bf16(af[f], wf, acc, 0, 0, 0);
        }
        const int co = ct * 16 + l15;
        const int ibase = i0 + p0 + lg * 4;
        size_t xa = ((size_t)n * CIN + co) * HW + ibase;
        f32x4 xv = *(const f32x4*)(x + xa);
        f32x4 pv = *(const f32x4*)(pe + co * 14400 + blockIdx.x * 120 + p0 + lg * 4);
        const float bias = bz[co];
        f32x4 o;
        #pragma unroll
        for (int r = 0; r < 4; ++r) o[r] = xv[r] + pv[r] + acc[r] + bias;
        *(f32x4*)(out + xa) = o;
    }
}

// ---------------------------------------------------------------------------
extern "C" void kernel_launch(void* const* d_in, const int* in_sizes, int n_in,
                              void* d_out, int out_size, void* d_ws, size_t ws_size,
                              hipStream_t stream) {
    const float* x  = (const float*)d_in[0];
    const float* pe = (const float*)d_in[1];
    const float* wq = (const float*)d_in[2];
    const float* bq = (const float*)d_in[3];
    const float* wk = (const float*)d_in[4];
    const float* bk = (const float*)d_in[5];
    const float* wv = (const float*)d_in[6];
    const float* bv = (const float*)d_in[7];
    const float* wz = (const float*)d_in[8];
    const float* bz = (const float*)d_in[9];
    float* out = (float*)d_out;

    char* ws = (char*)d_ws;
    // ws layout (bytes) — JS=4:
    //        0: wqkvb bf16 [288][192]          110,592 (pad 131072)
    //   131072: wzb   bf16 [192][96]            36,864 (pad 65536)
    //   196608: QF bf16 [8][128][6][64][8]    6,291,456
    //  6488064: KF bf16 (same shape)          6,291,456
    // 12779520: VF bf16 [8][64][3][2][2][64][8] 6,291,456
    // 19070976: zp bf16 [4][8][4096][96]     25,165,824
    // 44236800: lp f32 [4][8][4096]             524,288   (end 44,761,088)
    unsigned short* wqkvb = (unsigned short*)(ws);
    unsigned short* wzb   = (unsigned short*)(ws + 131072);
    unsigned short* QFb   = (unsigned short*)(ws + 196608);
    unsigned short* KFb   = (unsigned short*)(ws + 6488064);
    unsigned short* VFb   = (unsigned short*)(ws + 12779520);
    unsigned short* zpb   = (unsigned short*)(ws + 19070976);
    float*          lpb   = (float*)(ws + 44236800);

    convw_kernel<<<288, 256, 0, stream>>>(wq, wk, wv, wz, wqkvb, wzb);
    qkv_kernel<<<dim3(64, 8), 512, 0, stream>>>(x, pe, wqkvb, bq, bk, bv,
                                                QFb, KFb, VFb);
    attn_kernel<<<512, 256, 0, stream>>>(QFb, KFb, VFb, zpb, lpb);
    zproj_kernel<<<dim3(64, 8), 256, 0, stream>>>(zpb, lpb, wzb, bz, x, pe, out);
}